// Round 2
// baseline (1608.348 us; speedup 1.0000x reference)
//
#include <hip/hip_runtime.h>

#define BATCH   128
#define NUM_IN  4096
#define LVL     8
#define HID     32768
#define KH      32
#define OUTN    256
#define KOUT    64
#define SCALEA  4.9f

// Input u8 affine quantization range [-QR, QR]
#define QR      6.0f
#define QSTEP   (2.0f * QR / 255.0f)   // dequant scale
#define INV255  (1.0f / 255.0f)

// Slice geometry: 4 batch-slices of 32 batch elements (16 u8-pairs = 32 B per
// node per slice).  ext[s][j][l], l in 0..15.
// Deep levels claim work from per-XCD ticket queues (XCC_ID read from HW), so
// XCD x only ever gathers slice x&3: per-XCD act footprint is range*32 B,
// further range-split into 2 passes at levels 5-7 to stay under the 4 MiB L2.
#define NODES   266240              // NUM_IN + LVL*HID
#define SLICE_U (NODES * 16u)       // ushorts per slice = 4,259,840

#define TILE_H  16                  // h per block
#define QTILES  ((HID / 2) / TILE_H)  // 1024 tiles per queue (8 queues)

__device__ __forceinline__ unsigned short f2bf(float f) {
    unsigned u = __float_as_uint(f);
    u += 0x7FFFu + ((u >> 16) & 1u);   // round-to-nearest-even
    return (unsigned short)(u >> 16);
}
__device__ __forceinline__ float bf_lo(unsigned u) { return __uint_as_float(u << 16); }
__device__ __forceinline__ float bf_hi(unsigned u) { return __uint_as_float(u & 0xFFFF0000u); }

__device__ __forceinline__ unsigned q_in(float x) {   // input -> u8, range [-QR, QR]
    float t = (x + QR) * (255.0f / (2.0f * QR));
    t = fminf(fmaxf(t, 0.f), 255.f);
    return __float2uint_rn(t);
}

// ---------------------------------------------------------------------------
// Transpose x [B, NUM_IN] f32 -> in_bf (bf16 pairs, node-major full-batch, for
// level0) + ext[s][j<NUM_IN][l] (u8 pairs, sliced).  Also zeros the 64 ticket
// counters (runs before any deep_level in stream order).
// ---------------------------------------------------------------------------
__global__ __launch_bounds__(256) void transpose_x(const float* __restrict__ x,
                                                   unsigned* __restrict__ in_bf,
                                                   unsigned short* __restrict__ ext,
                                                   int* __restrict__ ctr) {
    __shared__ float lds[64][129];
    const int n0 = blockIdx.x * 64;
    const int t  = threadIdx.x;
    if (blockIdx.x == 0 && t < 64) ctr[t] = 0;
    #pragma unroll
    for (int it = 0; it < 32; ++it) {
        int i = it * 256 + t;
        int b = i >> 6;
        int n = i & 63;
        lds[n][b] = x[b * NUM_IN + n0 + n];
    }
    __syncthreads();
    #pragma unroll
    for (int it = 0; it < 16; ++it) {
        int i  = it * 256 + t;      // 64 nodes x 64 batch-pairs
        int n  = i >> 6;
        int bp = i & 63;
        float v0 = lds[n][2 * bp], v1 = lds[n][2 * bp + 1];
        in_bf[(n0 + n) * 64 + bp] = (unsigned)f2bf(v0) | ((unsigned)f2bf(v1) << 16);
        ext[(unsigned)(bp >> 4) * SLICE_U + (unsigned)(n0 + n) * 16u + (unsigned)(bp & 15)] =
            (unsigned short)(q_in(v0) | (q_in(v1) << 8));
    }
}

// ---------------------------------------------------------------------------
// Level 0: all sources are inputs. bf16 gathers from the 1 MB L2-resident
// in_bf table; writes u8 sigmoid acts into the SLICED ext table.
// ---------------------------------------------------------------------------
__global__ __launch_bounds__(256) void level0(const unsigned* __restrict__ in_bf,
                                              unsigned short* __restrict__ ext,
                                              const int* __restrict__ idx,
                                              const float* __restrict__ w) {
    const int lane = threadIdx.x & 63;
    int h = (blockIdx.x << 2) + (threadIdx.x >> 6);
    h = __builtin_amdgcn_readfirstlane(h);
    const int*   ip = idx + h * KH;
    const float* wp = w   + h * KH;
    float ax = 0.f, ay = 0.f;
    #pragma unroll
    for (int k = 0; k < KH; ++k) {
        int   j  = __builtin_amdgcn_readfirstlane(ip[k]);
        float wk = wp[k];
        unsigned v = in_bf[(unsigned)j * 64 + lane];
        ax = fmaf(wk, bf_lo(v), ax);
        ay = fmaf(wk, bf_hi(v), ay);
    }
    unsigned qx = __float2uint_rn(255.f / (1.f + __expf(-SCALEA * ax)));
    unsigned qy = __float2uint_rn(255.f / (1.f + __expf(-SCALEA * ay)));
    ext[(unsigned)(lane >> 4) * SLICE_U + (unsigned)(NUM_IN + h) * 16u + (unsigned)(lane & 15)] =
        (unsigned short)(qx | (qy << 8));
}

// ---------------------------------------------------------------------------
// Levels 1..7: work claimed from per-XCD ticket queues.  Queue q = XCC_ID
// covers slice q&3 (batch 32*(q&3)..) and h-half q>>2.  Steal order tries q^4
// first (same slice -> locality preserved).  npass range-splits the k-sum so
// the per-XCD act footprint stays under L2 capacity at deep levels.
// ---------------------------------------------------------------------------
__global__ __launch_bounds__(256) void deep_level(unsigned short* __restrict__ ext,
                                                  const int* __restrict__ idx,
                                                  const float* __restrict__ w,
                                                  int nbase,             // NUM_IN + l*HID
                                                  int* __restrict__ ctr, // 8 counters
                                                  int npass) {
    __shared__ unsigned long long tile[TILE_H * 33];
    __shared__ int sqt;
    int xcc;
    asm volatile("s_getreg_b32 %0, hwreg(HW_REG_XCC_ID)" : "=s"(xcc));
    xcc &= 7;
    const int tid = threadIdx.x;
    if (tid == 0) {
        int enc = -1;
        for (int a = 0; a < 8; ++a) {
            // a=0: own queue; a=1: same-slice partner (q^4); then neighbors.
            int cand = ((xcc + (a >> 1)) & 7) ^ ((a & 1) << 2);
            int tk = atomicAdd(&ctr[cand], 1);
            if (tk < QTILES) { enc = (cand << 16) | tk; break; }
        }
        sqt = enc;
    }
    __syncthreads();
    const int enc = sqt;
    if (enc < 0) return;
    const int q  = enc >> 16;
    const int tk = enc & 0xFFFF;
    const int s  = q & 3;
    const int hb = (q >> 2) * (HID / 2) + tk * TILE_H;

    #pragma unroll
    for (int it = 0; it < 2; ++it) {
        int e   = it * 256 + tid;           // 512 entries = 16 h x 32 k
        int h_l = e >> 5, k = e & 31;
        int gi  = (hb + h_l) * KH + k;
        unsigned ji = (unsigned)__builtin_nontemporal_load(idx + gi);
        float    wv = __builtin_nontemporal_load(w + gi);
        tile[h_l * 33 + k] =
            (unsigned long long)ji | ((unsigned long long)__float_as_uint(wv) << 32);
    }
    __syncthreads();

    const int lane = tid & 63;
    const int wid  = tid >> 6;
    const int l    = lane & 15;             // batch-pair within slice
    const int g    = lane >> 4;             // group -> h
    const int h_l  = wid * 4 + g;
    const unsigned cbase = (unsigned)s * (SLICE_U * 2u) + (unsigned)l * 2u;  // bytes

    float ax = 0.f, ay = 0.f, bias = 0.f;
    for (int p = 0; p < npass; ++p) {
        unsigned lo = (unsigned)((unsigned long long)nbase * (unsigned)p       / (unsigned)npass);
        unsigned hi = (unsigned)((unsigned long long)nbase * (unsigned)(p + 1) / (unsigned)npass);
        #pragma unroll
        for (int k = 0; k < KH; ++k) {
            unsigned long long jw = tile[h_l * 33 + k];   // broadcast within group
            unsigned j = (unsigned)jw;
            if (j >= lo && j < hi) {                      // group-uniform branch
                float wk = __uint_as_float((unsigned)(jw >> 32));
                bool isin = j < NUM_IN;
                float a = wk * (isin ? QSTEP : INV255);
                bias   += isin ? (-QR * wk) : 0.f;
                unsigned tt = *(const unsigned short*)((const char*)ext + (cbase + (j << 5)));
                ax = fmaf(a, (float)(tt & 0xFFu), ax);
                ay = fmaf(a, (float)(tt >> 8),   ay);
            }
        }
    }
    ax += bias;
    ay += bias;

    unsigned qx = __float2uint_rn(255.f / (1.f + __expf(-SCALEA * ax)));
    unsigned qy = __float2uint_rn(255.f / (1.f + __expf(-SCALEA * ay)));
    ext[(unsigned)s * SLICE_U + (unsigned)(nbase + hb + h_l) * 16u + (unsigned)l] =
        (unsigned short)(qx | (qy << 8));
}

// ---------------------------------------------------------------------------
// Output layer: sliced scheme, KO=64; 16 outputs per block, one slice. Tiny
// (2 MB traffic) -> no queue machinery.
// ---------------------------------------------------------------------------
__global__ __launch_bounds__(256) void output_layer(const unsigned short* __restrict__ ext,
                                                    const int* __restrict__ idx,
                                                    const float* __restrict__ w,
                                                    float* __restrict__ out) {
    __shared__ unsigned long long tile[16 * 65];
    const int t   = threadIdx.x;
    const int bid = blockIdx.x;
    const int s   = bid & 3;
    const int ob  = (bid >> 2) * 16;

    #pragma unroll
    for (int it = 0; it < 4; ++it) {
        int e   = it * 256 + t;             // 1024 entries = 16 o x 64 k
        int o_l = e >> 6, k = e & 63;
        int gi  = (ob + o_l) * KOUT + k;
        unsigned ji = (unsigned)__builtin_nontemporal_load(idx + gi);
        float    wv = __builtin_nontemporal_load(w + gi);
        tile[o_l * 65 + k] =
            (unsigned long long)ji | ((unsigned long long)__float_as_uint(wv) << 32);
    }
    __syncthreads();

    const int lane = t & 63;
    const int wid  = t >> 6;
    const int l    = lane & 15;
    const int g    = lane >> 4;
    const int o_l  = wid * 4 + g;
    const unsigned cbase = (unsigned)s * (SLICE_U * 2u) + (unsigned)l * 2u;

    float ax = 0.f, ay = 0.f, bias = 0.f;
    #pragma unroll
    for (int k = 0; k < KOUT; ++k) {
        unsigned long long jw = tile[o_l * 65 + k];
        unsigned j  = (unsigned)jw;
        float    wk = __uint_as_float((unsigned)(jw >> 32));
        bool isin = j < NUM_IN;
        float a = wk * (isin ? QSTEP : INV255);
        bias   += isin ? (-QR * wk) : 0.f;
        unsigned tt = *(const unsigned short*)((const char*)ext + (cbase + (j << 5)));
        ax = fmaf(a, (float)(tt & 0xFFu), ax);
        ay = fmaf(a, (float)(tt >> 8),   ay);
    }
    ax += bias;
    ay += bias;

    int o  = ob + o_l;
    int b0 = 2 * (s * 16 + l);
    out[(b0 + 0) * OUTN + o] = 1.f / (1.f + __expf(-SCALEA * ax));
    out[(b0 + 1) * OUTN + o] = 1.f / (1.f + __expf(-SCALEA * ay));
}

extern "C" void kernel_launch(void* const* d_in, const int* in_sizes, int n_in,
                              void* d_out, int out_size, void* d_ws, size_t ws_size,
                              hipStream_t stream) {
    // setup_inputs() order: x, w_hidden, w_out, idx_hidden, idx_out
    const float* x          = (const float*)d_in[0];
    const float* w_hidden   = (const float*)d_in[1];
    const float* w_out      = (const float*)d_in[2];
    const int*   idx_hidden = (const int*)  d_in[3];
    const int*   idx_out    = (const int*)  d_in[4];
    float* out = (float*)d_out;

    char* ws = (char*)d_ws;
    unsigned*       in_bf = (unsigned*)      (ws + 0);        // 1,048,576 B
    unsigned short* ext   = (unsigned short*)(ws + 1048576);  // 34,078,720 B
    int*            ctr   = (int*)           (ws + 1048576 + 34078720);  // 64 ints

    transpose_x<<<NUM_IN / 64, 256, 0, stream>>>(x, in_bf, ext, ctr);

    level0<<<HID / 4, 256, 0, stream>>>(in_bf, ext, idx_hidden, w_hidden);

    for (int l = 1; l < LVL; ++l) {
        int npass = (l >= 5) ? 2 : 1;   // keep per-pass footprint < 4 MiB/XCD
        deep_level<<<(HID / TILE_H) * 4, 256, 0, stream>>>(
            ext,
            idx_hidden + (size_t)l * HID * KH,
            w_hidden   + (size_t)l * HID * KH,
            NUM_IN + l * HID,
            ctr + (l - 1) * 8,
            npass);
    }
    output_layer<<<(OUTN / 16) * 4, 256, 0, stream>>>(ext, idx_out, w_out, out);
}

// Round 3
// 863.130 us; speedup vs baseline: 1.8634x; 1.8634x over previous
//
#include <hip/hip_runtime.h>

#define BATCH   128
#define NUM_IN  4096
#define LVL     8
#define HID     32768
#define KH      32
#define OUTN    256
#define KOUT    64
#define SCALEA  4.9f

// Input u8 affine quantization range [-QR, QR]
#define QR      6.0f
#define QSTEP   (2.0f * QR / 255.0f)   // dequant scale
#define INV255  (1.0f / 255.0f)

// Slice geometry: 8 batch-slices of 16 batch elements (8 u8-pairs = 16 B per
// node per slice).  ext[s][j][pos], pos in 0..7 (ushort pairs).
// deep blocks use slice = blockIdx & 7; under the round-robin blockIdx%8->XCD
// dispatch each XCD gathers EXACTLY ONE slice: per-XCD act footprint =
// range*16 B = 0.63 MB (L1) .. 3.8 MB (L7), L2-resident; levels 5-7 range-split
// into 2 passes (<=1.9 MB/pass) for conflict-miss margin.
#define NODES   266240              // NUM_IN + LVL*HID
#define SLICE_U (NODES * 8u)        // ushorts per slice = 2,129,920
#define SLICE_B (NODES * 16u)       // bytes per slice

__device__ __forceinline__ unsigned short f2bf(float f) {
    unsigned u = __float_as_uint(f);
    u += 0x7FFFu + ((u >> 16) & 1u);   // round-to-nearest-even
    return (unsigned short)(u >> 16);
}
__device__ __forceinline__ float bf_lo(unsigned u) { return __uint_as_float(u << 16); }
__device__ __forceinline__ float bf_hi(unsigned u) { return __uint_as_float(u & 0xFFFF0000u); }

__device__ __forceinline__ unsigned q_in(float x) {   // input -> u8, range [-QR, QR]
    float t = (x + QR) * (255.0f / (2.0f * QR));
    t = fminf(fmaxf(t, 0.f), 255.f);
    return __float2uint_rn(t);
}

// ---------------------------------------------------------------------------
// Transpose x [B, NUM_IN] f32 -> in_bf (bf16 pairs, node-major full-batch, for
// level0) + ext[s][j<NUM_IN][pos] (u8 pairs, 8-sliced).
// ---------------------------------------------------------------------------
__global__ __launch_bounds__(256) void transpose_x(const float* __restrict__ x,
                                                   unsigned* __restrict__ in_bf,
                                                   unsigned short* __restrict__ ext) {
    __shared__ float lds[64][129];
    const int n0 = blockIdx.x * 64;
    const int t  = threadIdx.x;
    #pragma unroll
    for (int it = 0; it < 32; ++it) {
        int i = it * 256 + t;
        int b = i >> 6;
        int n = i & 63;
        lds[n][b] = x[b * NUM_IN + n0 + n];
    }
    __syncthreads();
    #pragma unroll
    for (int it = 0; it < 16; ++it) {
        int i  = it * 256 + t;      // 64 nodes x 64 batch-pairs
        int n  = i >> 6;
        int bp = i & 63;
        float v0 = lds[n][2 * bp], v1 = lds[n][2 * bp + 1];
        in_bf[(n0 + n) * 64 + bp] = (unsigned)f2bf(v0) | ((unsigned)f2bf(v1) << 16);
        // 8-slice u8 layout: slice = bp>>3, pos = bp&7
        ext[(unsigned)(bp >> 3) * SLICE_U + (unsigned)(n0 + n) * 8u + (unsigned)(bp & 7)] =
            (unsigned short)(q_in(v0) | (q_in(v1) << 8));
    }
}

// ---------------------------------------------------------------------------
// Level 0: all sources are inputs. bf16 gathers from the 1 MB (L2-resident,
// proven by round-0 timing) in_bf table; writes u8 acts into 8-sliced ext.
// ---------------------------------------------------------------------------
__global__ __launch_bounds__(256) void level0(const unsigned* __restrict__ in_bf,
                                              unsigned short* __restrict__ ext,
                                              const int* __restrict__ idx,
                                              const float* __restrict__ w) {
    const int lane = threadIdx.x & 63;
    int h = (blockIdx.x << 2) + (threadIdx.x >> 6);
    h = __builtin_amdgcn_readfirstlane(h);
    const int*   ip = idx + h * KH;
    const float* wp = w   + h * KH;
    float ax = 0.f, ay = 0.f;
    #pragma unroll
    for (int k = 0; k < KH; ++k) {
        int   j  = __builtin_amdgcn_readfirstlane(ip[k]);
        float wk = wp[k];
        unsigned v = in_bf[(unsigned)j * 64 + lane];
        ax = fmaf(wk, bf_lo(v), ax);
        ay = fmaf(wk, bf_hi(v), ay);
    }
    unsigned qx = __float2uint_rn(255.f / (1.f + __expf(-SCALEA * ax)));
    unsigned qy = __float2uint_rn(255.f / (1.f + __expf(-SCALEA * ay)));
    ext[(unsigned)(lane >> 3) * SLICE_U + (unsigned)(NUM_IN + h) * 8u + (unsigned)(lane & 7)] =
        (unsigned short)(qx | (qy << 8));
}

// ---------------------------------------------------------------------------
// Levels 1..7: slice = blockIdx&7 (one XCD per slice under round-robin).
// Block = 32 h x 1 slice; wave = 8 groups x 8 lanes; group g computes one h
// over its slice's 16 batch values (one 16-B request per (h,k)).
// npass=2 at deep levels splits the k-sum by source range [0,mid),[mid,nbase)
// so the per-pass footprint stays <=1.9 MB/XCD.  No atomics / s_getreg / u64
// division (round-2 post-mortem: those caused VGPR 116 + 22% occupancy).
// ---------------------------------------------------------------------------
__global__ __launch_bounds__(256) void deep_level(unsigned short* __restrict__ ext,
                                                  const int* __restrict__ idx,
                                                  const float* __restrict__ w,
                                                  int nbase,   // NUM_IN + l*HID
                                                  int npass) { // 1 or 2
    __shared__ unsigned long long tile[32 * 33];
    const int t   = threadIdx.x;
    const int bid = blockIdx.x;
    const int s   = bid & 7;            // slice == XCD
    const int hb  = (bid >> 3) * 32;    // 32 h per block

    #pragma unroll
    for (int it = 0; it < 4; ++it) {
        int e   = it * 256 + t;         // 1024 entries = 32 h x 32 k
        int h_l = e >> 5, k = e & 31;
        int gi  = (hb + h_l) * KH + k;
        unsigned ji = (unsigned)__builtin_nontemporal_load(idx + gi);
        float    wv = __builtin_nontemporal_load(w + gi);
        tile[h_l * 33 + k] =
            (unsigned long long)ji | ((unsigned long long)__float_as_uint(wv) << 32);
    }
    __syncthreads();

    const int lane = t & 63;
    const int wid  = t >> 6;
    const int pos  = lane & 7;          // batch-pair within slice
    const int g    = lane >> 3;         // group -> h
    const int h_l  = wid * 8 + g;
    const char* base = (const char*)ext + (unsigned)s * SLICE_B + (unsigned)pos * 2u;

    const unsigned mid = (npass == 1) ? (unsigned)nbase : ((unsigned)nbase >> 1);

    float ax = 0.f, ay = 0.f, bias = 0.f;
    for (int p = 0; p < npass; ++p) {
        const unsigned lo = p ? mid : 0u;
        const unsigned hi = p ? (unsigned)nbase : mid;
        #pragma unroll
        for (int k = 0; k < KH; ++k) {
            unsigned long long jw = tile[h_l * 33 + k];   // broadcast within group
            unsigned j = (unsigned)jw;
            if (j >= lo && j < hi) {                      // group-uniform predicate
                float wk = __uint_as_float((unsigned)(jw >> 32));
                bool isin = j < NUM_IN;
                float a = wk * (isin ? QSTEP : INV255);
                bias   += isin ? (-QR * wk) : 0.f;
                unsigned tt = *(const unsigned short*)(base + ((unsigned)j << 4));
                ax = fmaf(a, (float)(tt & 0xFFu), ax);
                ay = fmaf(a, (float)(tt >> 8),   ay);
            }
        }
    }
    ax += bias;
    ay += bias;

    unsigned qx = __float2uint_rn(255.f / (1.f + __expf(-SCALEA * ax)));
    unsigned qy = __float2uint_rn(255.f / (1.f + __expf(-SCALEA * ay)));
    ext[(unsigned)s * SLICE_U + (unsigned)(nbase + hb + h_l) * 8u + (unsigned)pos] =
        (unsigned short)(qx | (qy << 8));
}

// ---------------------------------------------------------------------------
// Output layer: same 8-slice scheme, KO=64; 32 outputs per block. Tiny.
// ---------------------------------------------------------------------------
__global__ __launch_bounds__(256) void output_layer(const unsigned short* __restrict__ ext,
                                                    const int* __restrict__ idx,
                                                    const float* __restrict__ w,
                                                    float* __restrict__ out) {
    __shared__ unsigned long long tile[32 * 65];
    const int t   = threadIdx.x;
    const int bid = blockIdx.x;
    const int s   = bid & 7;
    const int ob  = (bid >> 3) * 32;

    #pragma unroll
    for (int it = 0; it < 8; ++it) {
        int e   = it * 256 + t;         // 2048 entries = 32 o x 64 k
        int o_l = e >> 6, k = e & 63;
        int gi  = (ob + o_l) * KOUT + k;
        unsigned ji = (unsigned)__builtin_nontemporal_load(idx + gi);
        float    wv = __builtin_nontemporal_load(w + gi);
        tile[o_l * 65 + k] =
            (unsigned long long)ji | ((unsigned long long)__float_as_uint(wv) << 32);
    }
    __syncthreads();

    const int lane = t & 63;
    const int wid  = t >> 6;
    const int pos  = lane & 7;
    const int g    = lane >> 3;
    const int o_l  = wid * 8 + g;
    const char* base = (const char*)ext + (unsigned)s * SLICE_B + (unsigned)pos * 2u;

    float ax = 0.f, ay = 0.f, bias = 0.f;
    #pragma unroll
    for (int k = 0; k < KOUT; ++k) {
        unsigned long long jw = tile[o_l * 65 + k];
        unsigned j  = (unsigned)jw;
        float    wk = __uint_as_float((unsigned)(jw >> 32));
        bool isin = j < NUM_IN;
        float a = wk * (isin ? QSTEP : INV255);
        bias   += isin ? (-QR * wk) : 0.f;
        unsigned tt = *(const unsigned short*)(base + ((unsigned)j << 4));
        ax = fmaf(a, (float)(tt & 0xFFu), ax);
        ay = fmaf(a, (float)(tt >> 8),   ay);
    }
    ax += bias;
    ay += bias;

    int o  = ob + o_l;
    int b0 = s * 16 + 2 * pos;
    out[(b0 + 0) * OUTN + o] = 1.f / (1.f + __expf(-SCALEA * ax));
    out[(b0 + 1) * OUTN + o] = 1.f / (1.f + __expf(-SCALEA * ay));
}

extern "C" void kernel_launch(void* const* d_in, const int* in_sizes, int n_in,
                              void* d_out, int out_size, void* d_ws, size_t ws_size,
                              hipStream_t stream) {
    // setup_inputs() order: x, w_hidden, w_out, idx_hidden, idx_out
    const float* x          = (const float*)d_in[0];
    const float* w_hidden   = (const float*)d_in[1];
    const float* w_out      = (const float*)d_in[2];
    const int*   idx_hidden = (const int*)  d_in[3];
    const int*   idx_out    = (const int*)  d_in[4];
    float* out = (float*)d_out;

    char* ws = (char*)d_ws;
    unsigned*       in_bf = (unsigned*)      (ws + 0);        // 1,048,576 B
    unsigned short* ext   = (unsigned short*)(ws + 1048576);  // 8 * 4,259,840 B = 34,078,720 B

    transpose_x<<<NUM_IN / 64, 256, 0, stream>>>(x, in_bf, ext);

    level0<<<HID / 4, 256, 0, stream>>>(in_bf, ext, idx_hidden, w_hidden);

    for (int l = 1; l < LVL; ++l) {
        int npass = (l >= 5) ? 2 : 1;   // per-pass footprint <= 1.9 MB/XCD
        deep_level<<<(HID / 32) * 8, 256, 0, stream>>>(
            ext,
            idx_hidden + (size_t)l * HID * KH,
            w_hidden   + (size_t)l * HID * KH,
            NUM_IN + l * HID,
            npass);
    }
    output_layer<<<(OUTN / 32) * 8, 256, 0, stream>>>(ext, idx_out, w_out, out);
}

// Round 5
// 536.940 us; speedup vs baseline: 2.9954x; 1.6075x over previous
//
#include <hip/hip_runtime.h>

#define BATCH   128
#define NUM_IN  4096
#define LVL     8
#define HID     32768
#define KH      32
#define OUTN    256
#define KOUT    64
#define SCALEA  4.9f

// Input u8 affine quantization range [-QR, QR]
#define QR      6.0f
#define QSTEP   (2.0f * QR / 255.0f)   // dequant scale
#define INV255  (1.0f / 255.0f)

// Slice geometry: 8 batch-slices of 16 batch elements (8 u8-pairs = 16 B per
// node per slice).  ext[s][j][pos], pos in 0..7 (ushort pairs).
// deep blocks use slice = blockIdx & 7; under the round-robin blockIdx%8->XCD
// dispatch each XCD gathers EXACTLY ONE slice.  Worst footprint (level 7):
// 233472 nodes * 16 B = 3.73 MB < 4 MiB L2 -> single pass fits at EVERY level
// (round-3 FETCH=48MB proved the slice stays resident; its 150us came from the
// pass-predicate branches destroying memory-level parallelism -> removed).
#define NODES   266240              // NUM_IN + LVL*HID
#define SLICE_U (NODES * 8u)        // ushorts per slice = 2,129,920
#define SLICE_B (NODES * 16u)       // bytes per slice

__device__ __forceinline__ unsigned short f2bf(float f) {
    unsigned u = __float_as_uint(f);
    u += 0x7FFFu + ((u >> 16) & 1u);   // round-to-nearest-even
    return (unsigned short)(u >> 16);
}
__device__ __forceinline__ float bf_lo(unsigned u) { return __uint_as_float(u << 16); }
__device__ __forceinline__ float bf_hi(unsigned u) { return __uint_as_float(u & 0xFFFF0000u); }

__device__ __forceinline__ unsigned q_in(float x) {   // input -> u8, range [-QR, QR]
    float t = (x + QR) * (255.0f / (2.0f * QR));
    t = fminf(fmaxf(t, 0.f), 255.f);
    return __float2uint_rn(t);
}

// ---------------------------------------------------------------------------
// Transpose x [B, NUM_IN] f32 -> in_bf (bf16 pairs, node-major full-batch, for
// level0) + ext[s][j<NUM_IN][pos] (u8 pairs, 8-sliced).
// ---------------------------------------------------------------------------
__global__ __launch_bounds__(256) void transpose_x(const float* __restrict__ x,
                                                   unsigned* __restrict__ in_bf,
                                                   unsigned short* __restrict__ ext) {
    __shared__ float lds[64][129];
    const int n0 = blockIdx.x * 64;
    const int t  = threadIdx.x;
    #pragma unroll
    for (int it = 0; it < 32; ++it) {
        int i = it * 256 + t;
        int b = i >> 6;
        int n = i & 63;
        lds[n][b] = x[b * NUM_IN + n0 + n];
    }
    __syncthreads();
    #pragma unroll
    for (int it = 0; it < 16; ++it) {
        int i  = it * 256 + t;      // 64 nodes x 64 batch-pairs
        int n  = i >> 6;
        int bp = i & 63;
        float v0 = lds[n][2 * bp], v1 = lds[n][2 * bp + 1];
        in_bf[(n0 + n) * 64 + bp] = (unsigned)f2bf(v0) | ((unsigned)f2bf(v1) << 16);
        // 8-slice u8 layout: slice = bp>>3, pos = bp&7
        ext[(unsigned)(bp >> 3) * SLICE_U + (unsigned)(n0 + n) * 8u + (unsigned)(bp & 7)] =
            (unsigned short)(q_in(v0) | (q_in(v1) << 8));
    }
}

// ---------------------------------------------------------------------------
// Level 0: all sources are inputs. bf16 gathers from the 1 MB L2-resident
// in_bf table; writes u8 acts into 8-sliced ext.
// ---------------------------------------------------------------------------
__global__ __launch_bounds__(256) void level0(const unsigned* __restrict__ in_bf,
                                              unsigned short* __restrict__ ext,
                                              const int* __restrict__ idx,
                                              const float* __restrict__ w) {
    const int lane = threadIdx.x & 63;
    int h = (blockIdx.x << 2) + (threadIdx.x >> 6);
    h = __builtin_amdgcn_readfirstlane(h);
    const int*   ip = idx + h * KH;
    const float* wp = w   + h * KH;
    float ax = 0.f, ay = 0.f;
    #pragma unroll
    for (int k = 0; k < KH; ++k) {
        int   j  = __builtin_amdgcn_readfirstlane(ip[k]);
        float wk = wp[k];
        unsigned v = in_bf[(unsigned)j * 64 + lane];
        ax = fmaf(wk, bf_lo(v), ax);
        ay = fmaf(wk, bf_hi(v), ay);
    }
    unsigned qx = __float2uint_rn(255.f / (1.f + __expf(-SCALEA * ax)));
    unsigned qy = __float2uint_rn(255.f / (1.f + __expf(-SCALEA * ay)));
    ext[(unsigned)(lane >> 3) * SLICE_U + (unsigned)(NUM_IN + h) * 8u + (unsigned)(lane & 7)] =
        (unsigned short)(qx | (qy << 8));
}

// ---------------------------------------------------------------------------
// Levels 1..7: slice = blockIdx&7 (one XCD per slice under round-robin).
// Block = 32 h x 1 slice; wave = 8 groups x 8 lanes; group g computes one h
// over its slice's 16 batch values (one 16-B request per (h,k)).
// Inner loop is UNCONDITIONAL and branch-free (round-3 post-mortem: runtime
// pass-predicates serialized the 32 loads -> 150us latency wall).  All 32
// per-lane loads are independent -> full memory-level parallelism.
// ---------------------------------------------------------------------------
__global__ __launch_bounds__(256) void deep_level(unsigned short* __restrict__ ext,
                                                  const int* __restrict__ idx,
                                                  const float* __restrict__ w,
                                                  int nbase) {  // NUM_IN + l*HID
    __shared__ unsigned long long tile[32 * 33];
    const int t   = threadIdx.x;
    const int bid = blockIdx.x;
    const int s   = bid & 7;            // slice == XCD
    const int hb  = (bid >> 3) * 32;    // 32 h per block

    #pragma unroll
    for (int it = 0; it < 4; ++it) {
        int e   = it * 256 + t;         // 1024 entries = 32 h x 32 k
        int h_l = e >> 5, k = e & 31;
        int gi  = (hb + h_l) * KH + k;
        unsigned ji = (unsigned)__builtin_nontemporal_load(idx + gi);
        float    wv = __builtin_nontemporal_load(w + gi);
        tile[h_l * 33 + k] =
            (unsigned long long)ji | ((unsigned long long)__float_as_uint(wv) << 32);
    }
    __syncthreads();

    const int lane = t & 63;
    const int wid  = t >> 6;
    const int pos  = lane & 7;          // batch-pair within slice
    const int g    = lane >> 3;         // group -> h
    const int h_l  = wid * 8 + g;
    const char* base = (const char*)ext + (unsigned)s * SLICE_B + (unsigned)pos * 2u;

    float ax = 0.f, ay = 0.f, bias = 0.f;
    #pragma unroll
    for (int k = 0; k < KH; ++k) {
        unsigned long long jw = tile[h_l * 33 + k];   // broadcast within group
        unsigned j  = (unsigned)jw;
        float    wk = __uint_as_float((unsigned)(jw >> 32));
        bool isin = j < NUM_IN;
        float a = wk * (isin ? QSTEP : INV255);
        bias   += isin ? (-QR * wk) : 0.f;
        unsigned tt = *(const unsigned short*)(base + ((unsigned)j << 4));
        ax = fmaf(a, (float)(tt & 0xFFu), ax);
        ay = fmaf(a, (float)(tt >> 8),   ay);
    }
    ax += bias;
    ay += bias;

    unsigned qx = __float2uint_rn(255.f / (1.f + __expf(-SCALEA * ax)));
    unsigned qy = __float2uint_rn(255.f / (1.f + __expf(-SCALEA * ay)));
    ext[(unsigned)s * SLICE_U + (unsigned)(nbase + hb + h_l) * 8u + (unsigned)pos] =
        (unsigned short)(qx | (qy << 8));
}

// ---------------------------------------------------------------------------
// Output layer: same 8-slice scheme, KO=64; 32 outputs per block. Tiny.
// ---------------------------------------------------------------------------
__global__ __launch_bounds__(256) void output_layer(const unsigned short* __restrict__ ext,
                                                    const int* __restrict__ idx,
                                                    const float* __restrict__ w,
                                                    float* __restrict__ out) {
    __shared__ unsigned long long tile[32 * 65];
    const int t   = threadIdx.x;
    const int bid = blockIdx.x;
    const int s   = bid & 7;
    const int ob  = (bid >> 3) * 32;

    #pragma unroll
    for (int it = 0; it < 8; ++it) {
        int e   = it * 256 + t;         // 2048 entries = 32 o x 64 k
        int o_l = e >> 6, k = e & 63;
        int gi  = (ob + o_l) * KOUT + k;
        unsigned ji = (unsigned)__builtin_nontemporal_load(idx + gi);
        float    wv = __builtin_nontemporal_load(w + gi);
        tile[o_l * 65 + k] =
            (unsigned long long)ji | ((unsigned long long)__float_as_uint(wv) << 32);
    }
    __syncthreads();

    const int lane = t & 63;
    const int wid  = t >> 6;
    const int pos  = lane & 7;
    const int g    = lane >> 3;
    const int o_l  = wid * 8 + g;
    const char* base = (const char*)ext + (unsigned)s * SLICE_B + (unsigned)pos * 2u;

    float ax = 0.f, ay = 0.f, bias = 0.f;
    #pragma unroll
    for (int k = 0; k < KOUT; ++k) {
        unsigned long long jw = tile[o_l * 65 + k];
        unsigned j  = (unsigned)jw;
        float    wk = __uint_as_float((unsigned)(jw >> 32));
        bool isin = j < NUM_IN;
        float a = wk * (isin ? QSTEP : INV255);
        bias   += isin ? (-QR * wk) : 0.f;
        unsigned tt = *(const unsigned short*)(base + ((unsigned)j << 4));
        ax = fmaf(a, (float)(tt & 0xFFu), ax);
        ay = fmaf(a, (float)(tt >> 8),   ay);
    }
    ax += bias;
    ay += bias;

    int o  = ob + o_l;
    int b0 = s * 16 + 2 * pos;
    out[(b0 + 0) * OUTN + o] = 1.f / (1.f + __expf(-SCALEA * ax));
    out[(b0 + 1) * OUTN + o] = 1.f / (1.f + __expf(-SCALEA * ay));
}

extern "C" void kernel_launch(void* const* d_in, const int* in_sizes, int n_in,
                              void* d_out, int out_size, void* d_ws, size_t ws_size,
                              hipStream_t stream) {
    // setup_inputs() order: x, w_hidden, w_out, idx_hidden, idx_out
    const float* x          = (const float*)d_in[0];
    const float* w_hidden   = (const float*)d_in[1];
    const float* w_out      = (const float*)d_in[2];
    const int*   idx_hidden = (const int*)  d_in[3];
    const int*   idx_out    = (const int*)  d_in[4];
    float* out = (float*)d_out;

    char* ws = (char*)d_ws;
    unsigned*       in_bf = (unsigned*)      (ws + 0);        // 1,048,576 B
    unsigned short* ext   = (unsigned short*)(ws + 1048576);  // 8 * 4,259,840 B = 34,078,720 B

    transpose_x<<<NUM_IN / 64, 256, 0, stream>>>(x, in_bf, ext);

    level0<<<HID / 4, 256, 0, stream>>>(in_bf, ext, idx_hidden, w_hidden);

    for (int l = 1; l < LVL; ++l) {
        deep_level<<<(HID / 32) * 8, 256, 0, stream>>>(
            ext,
            idx_hidden + (size_t)l * HID * KH,
            w_hidden   + (size_t)l * HID * KH,
            NUM_IN + l * HID);
    }
    output_layer<<<(OUTN / 32) * 8, 256, 0, stream>>>(ext, idx_out, w_out, out);
}

// Round 6
// 376.104 us; speedup vs baseline: 4.2763x; 1.4276x over previous
//
#include <hip/hip_runtime.h>

#define BATCH   128
#define NUM_IN  4096
#define LVL     8
#define HID     32768
#define KH      32
#define OUTN    256
#define KOUT    64
#define SCALEA  4.9f

// Input u8 affine quantization range [-QR, QR]
#define QR      6.0f
#define QSTEP   (2.0f * QR / 255.0f)   // dequant scale
#define INV255  (1.0f / 255.0f)

#define NODES   266240              // NUM_IN + LVL*HID

// Dual act tables (both u8 pairs), written by every producer:
//  ext128[node][bp0..63]  : full-batch 128-B records  -> L3-path gathers
//  ext16 [s][node][pos0..7]: 8 batch-slices, 16-B/node -> L2-path gathers
//   (slice s = XCD s under round-robin blockIdx%8; footprint <= 3.73 MB/XCD)
// Level split: h < H3 gather via L3 path (L3-BW-bound, ~3.7 TB/s measured
// round-0 => 36us/level at f=1); h >= H3 via L2 path (request-rate-bound,
// 65us/level at f=0 measured round-5). Concurrent mix uses both resources.
#define H3      24576               // L3-path rows per level (f = 0.75)
#define NB3     (H3 / 4)            // 6144 L3-path blocks (4 h each), %8==0
#define H2      (HID - H3)          // 8192 L2-path rows
#define SLICE_U (NODES * 8u)        // ushorts per ext16 slice
#define SLICE_B (NODES * 16u)       // bytes per ext16 slice

__device__ __forceinline__ unsigned short f2bf(float f) {
    unsigned u = __float_as_uint(f);
    u += 0x7FFFu + ((u >> 16) & 1u);   // round-to-nearest-even
    return (unsigned short)(u >> 16);
}
__device__ __forceinline__ float bf_lo(unsigned u) { return __uint_as_float(u << 16); }
__device__ __forceinline__ float bf_hi(unsigned u) { return __uint_as_float(u & 0xFFFF0000u); }

__device__ __forceinline__ unsigned q_in(float x) {   // input -> u8, range [-QR, QR]
    float t = (x + QR) * (255.0f / (2.0f * QR));
    t = fminf(fmaxf(t, 0.f), 255.f);
    return __float2uint_rn(t);
}

// ---------------------------------------------------------------------------
// Transpose x [B, NUM_IN] f32 -> in_bf (bf16 pairs, for level0) + input region
// of BOTH act tables.
// ---------------------------------------------------------------------------
__global__ __launch_bounds__(256) void transpose_x(const float* __restrict__ x,
                                                   unsigned* __restrict__ in_bf,
                                                   unsigned short* __restrict__ ext128,
                                                   unsigned short* __restrict__ ext16) {
    __shared__ float lds[64][129];
    const int n0 = blockIdx.x * 64;
    const int t  = threadIdx.x;
    #pragma unroll
    for (int it = 0; it < 32; ++it) {
        int i = it * 256 + t;
        int b = i >> 6;
        int n = i & 63;
        lds[n][b] = x[b * NUM_IN + n0 + n];
    }
    __syncthreads();
    #pragma unroll
    for (int it = 0; it < 16; ++it) {
        int i  = it * 256 + t;      // 64 nodes x 64 batch-pairs
        int n  = i >> 6;
        int bp = i & 63;
        float v0 = lds[n][2 * bp], v1 = lds[n][2 * bp + 1];
        in_bf[(n0 + n) * 64 + bp] = (unsigned)f2bf(v0) | ((unsigned)f2bf(v1) << 16);
        unsigned short q = (unsigned short)(q_in(v0) | (q_in(v1) << 8));
        ext128[(unsigned)(n0 + n) * 64u + (unsigned)bp] = q;
        ext16[(unsigned)(bp >> 3) * SLICE_U + (unsigned)(n0 + n) * 8u + (unsigned)(bp & 7)] = q;
    }
}

// ---------------------------------------------------------------------------
// Level 0: all sources are inputs. bf16 gathers from the 1 MB L2-resident
// in_bf table; dual-writes u8 acts.
// ---------------------------------------------------------------------------
__global__ __launch_bounds__(256) void level0(const unsigned* __restrict__ in_bf,
                                              unsigned short* __restrict__ ext128,
                                              unsigned short* __restrict__ ext16,
                                              const int* __restrict__ idx,
                                              const float* __restrict__ w) {
    const int lane = threadIdx.x & 63;
    int h = (blockIdx.x << 2) + (threadIdx.x >> 6);
    h = __builtin_amdgcn_readfirstlane(h);
    const int*   ip = idx + h * KH;
    const float* wp = w   + h * KH;
    float ax = 0.f, ay = 0.f;
    #pragma unroll
    for (int k = 0; k < KH; ++k) {
        int   j  = __builtin_amdgcn_readfirstlane(ip[k]);
        float wk = wp[k];
        unsigned v = in_bf[(unsigned)j * 64 + lane];
        ax = fmaf(wk, bf_lo(v), ax);
        ay = fmaf(wk, bf_hi(v), ay);
    }
    unsigned qx = __float2uint_rn(255.f / (1.f + __expf(-SCALEA * ax)));
    unsigned qy = __float2uint_rn(255.f / (1.f + __expf(-SCALEA * ay)));
    unsigned short q = (unsigned short)(qx | (qy << 8));
    ext128[(unsigned)(NUM_IN + h) * 64u + (unsigned)lane] = q;
    ext16[(unsigned)(lane >> 3) * SLICE_U + (unsigned)(NUM_IN + h) * 8u + (unsigned)(lane & 7)] = q;
}

// ---------------------------------------------------------------------------
// Levels 1..7, dual-path:
//  blocks [0, NB3): L3 path — round-0 structure: wave = one h, 64 lanes cover
//    full batch, one contiguous 128-B NT gather per (h,k). L3-BW-bound.
//  blocks [NB3, NB3+H2/32*8): L2 path — round-5 structure: slice = bid&7
//    (== XCD), 32 h per block, 16-B L2-local gather per (h,k,slice).
// Both write both tables; identical per-h arithmetic (k-ascending fmaf chain).
// ---------------------------------------------------------------------------
__global__ __launch_bounds__(256) void deep_dual(unsigned short* __restrict__ ext128,
                                                 unsigned short* __restrict__ ext16,
                                                 const int* __restrict__ idx,
                                                 const float* __restrict__ w,
                                                 int nbase) {  // NUM_IN + l*HID
    __shared__ unsigned long long tile[32 * 33];
    const int t   = threadIdx.x;
    const int bid = blockIdx.x;
    const int lane = t & 63;
    const int wid  = t >> 6;

    if (bid < NB3) {
        // ---------------- L3 path: full-batch 128-B records ----------------
        int h = (bid << 2) + wid;
        h = __builtin_amdgcn_readfirstlane(h);
        const int*   ip = idx + h * KH;
        const float* wp = w   + h * KH;
        float ax = 0.f, ay = 0.f, bias = 0.f;
        #pragma unroll
        for (int k = 0; k < KH; ++k) {
            int   j  = __builtin_amdgcn_readfirstlane(ip[k]);
            float wk = wp[k];
            bool isin = (j < NUM_IN);
            float a = wk * (isin ? QSTEP : INV255);
            bias   += isin ? (-QR * wk) : 0.f;
            unsigned tt = __builtin_nontemporal_load(
                ext128 + (unsigned)j * 64u + (unsigned)lane);
            ax = fmaf(a, (float)(tt & 0xFFu), ax);
            ay = fmaf(a, (float)(tt >> 8),   ay);
        }
        ax += bias;
        ay += bias;
        unsigned qx = __float2uint_rn(255.f / (1.f + __expf(-SCALEA * ax)));
        unsigned qy = __float2uint_rn(255.f / (1.f + __expf(-SCALEA * ay)));
        unsigned short q = (unsigned short)(qx | (qy << 8));
        ext128[(unsigned)(nbase + h) * 64u + (unsigned)lane] = q;
        ext16[(unsigned)(lane >> 3) * SLICE_U + (unsigned)(nbase + h) * 8u + (unsigned)(lane & 7)] = q;
        return;
    }

    // ------------------ L2 path: 16-B sliced records -----------------------
    const int bid2 = bid - NB3;
    const int s    = bid2 & 7;            // slice == XCD (NB3 % 8 == 0)
    const int hb   = H3 + (bid2 >> 3) * 32;

    #pragma unroll
    for (int it = 0; it < 4; ++it) {
        int e   = it * 256 + t;           // 1024 entries = 32 h x 32 k
        int h_l = e >> 5, k = e & 31;
        int gi  = (hb + h_l) * KH + k;
        unsigned ji = (unsigned)__builtin_nontemporal_load(idx + gi);
        float    wv = __builtin_nontemporal_load(w + gi);
        tile[h_l * 33 + k] =
            (unsigned long long)ji | ((unsigned long long)__float_as_uint(wv) << 32);
    }
    __syncthreads();

    const int pos  = lane & 7;            // batch-pair within slice
    const int g    = lane >> 3;           // group -> h
    const int h_l  = wid * 8 + g;
    const char* base = (const char*)ext16 + (unsigned)s * SLICE_B + (unsigned)pos * 2u;

    float ax = 0.f, ay = 0.f, bias = 0.f;
    #pragma unroll
    for (int k = 0; k < KH; ++k) {
        unsigned long long jw = tile[h_l * 33 + k];   // broadcast within group
        unsigned j  = (unsigned)jw;
        float    wk = __uint_as_float((unsigned)(jw >> 32));
        bool isin = j < NUM_IN;
        float a = wk * (isin ? QSTEP : INV255);
        bias   += isin ? (-QR * wk) : 0.f;
        unsigned tt = *(const unsigned short*)(base + ((unsigned)j << 4));
        ax = fmaf(a, (float)(tt & 0xFFu), ax);
        ay = fmaf(a, (float)(tt >> 8),   ay);
    }
    ax += bias;
    ay += bias;

    unsigned qx = __float2uint_rn(255.f / (1.f + __expf(-SCALEA * ax)));
    unsigned qy = __float2uint_rn(255.f / (1.f + __expf(-SCALEA * ay)));
    unsigned short q = (unsigned short)(qx | (qy << 8));
    ext16[(unsigned)s * SLICE_U + (unsigned)(nbase + hb + h_l) * 8u + (unsigned)pos] = q;
    ext128[(unsigned)(nbase + hb + h_l) * 64u + (unsigned)(s * 8 + pos)] = q;
}

// ---------------------------------------------------------------------------
// Output layer: tiny (O=256); round-0 structure on ext128.
// ---------------------------------------------------------------------------
__global__ __launch_bounds__(256) void output_layer(const unsigned short* __restrict__ ext128,
                                                    const int* __restrict__ idx,
                                                    const float* __restrict__ w,
                                                    float* __restrict__ out) {
    const int lane = threadIdx.x & 63;
    int o = (blockIdx.x << 2) + (threadIdx.x >> 6);
    o = __builtin_amdgcn_readfirstlane(o);
    const int*   ip = idx + o * KOUT;
    const float* wp = w   + o * KOUT;

    float ax = 0.f, ay = 0.f, bias = 0.f;
    #pragma unroll
    for (int k = 0; k < KOUT; ++k) {
        int   j  = __builtin_amdgcn_readfirstlane(ip[k]);
        float wk = wp[k];
        bool isin = (j < NUM_IN);
        float a = wk * (isin ? QSTEP : INV255);
        bias   += isin ? (-QR * wk) : 0.f;
        unsigned tt = ext128[(unsigned)j * 64u + (unsigned)lane];
        ax = fmaf(a, (float)(tt & 0xFFu), ax);
        ay = fmaf(a, (float)(tt >> 8),   ay);
    }
    ax += bias;
    ay += bias;
    out[(2 * lane + 0) * OUTN + o] = 1.f / (1.f + __expf(-SCALEA * ax));
    out[(2 * lane + 1) * OUTN + o] = 1.f / (1.f + __expf(-SCALEA * ay));
}

extern "C" void kernel_launch(void* const* d_in, const int* in_sizes, int n_in,
                              void* d_out, int out_size, void* d_ws, size_t ws_size,
                              hipStream_t stream) {
    // setup_inputs() order: x, w_hidden, w_out, idx_hidden, idx_out
    const float* x          = (const float*)d_in[0];
    const float* w_hidden   = (const float*)d_in[1];
    const float* w_out      = (const float*)d_in[2];
    const int*   idx_hidden = (const int*)  d_in[3];
    const int*   idx_out    = (const int*)  d_in[4];
    float* out = (float*)d_out;

    char* ws = (char*)d_ws;
    unsigned*       in_bf  = (unsigned*)      (ws + 0);                    //  1,048,576 B
    unsigned short* ext128 = (unsigned short*)(ws + 1048576);              // 34,078,720 B
    unsigned short* ext16  = (unsigned short*)(ws + 1048576 + 34078720);   // 34,078,720 B

    transpose_x<<<NUM_IN / 64, 256, 0, stream>>>(x, in_bf, ext128, ext16);

    level0<<<HID / 4, 256, 0, stream>>>(in_bf, ext128, ext16, idx_hidden, w_hidden);

    const int grid_deep = NB3 + (H2 / 32) * 8;   // 6144 + 2048 = 8192
    for (int l = 1; l < LVL; ++l) {
        deep_dual<<<grid_deep, 256, 0, stream>>>(
            ext128, ext16,
            idx_hidden + (size_t)l * HID * KH,
            w_hidden   + (size_t)l * HID * KH,
            NUM_IN + l * HID);
    }
    output_layer<<<OUTN / 4, 256, 0, stream>>>(ext128, idx_out, w_out, out);
}